// Round 3
// baseline (597.530 us; speedup 1.0000x reference)
//
#include <hip/hip_runtime.h>

#define EPS_F 0.1f
#define SCAN_THREADS 1024
#define SCAN_ITEMS 12   // N / SCAN_THREADS = 12288 / 1024
#define ROW_THREADS 1024

// -------------------------------------------------------------------------
// Kernel 1: single-block scan. Computes center/err per element, the
// inclusive cumsum of the selection mask (row assignment), and the INVERSE
// mapping inv[row] = column (or -1 if the row has no selected element).
// Outputs go to workspace: center[N] f32, err[N] f32, inv[N+1] i32.
// -------------------------------------------------------------------------
__global__ __launch_bounds__(SCAN_THREADS) void scan_kernel(
    const float* __restrict__ x,
    float* __restrict__ center,
    float* __restrict__ err,
    int*   __restrict__ inv,
    int N)
{
    __shared__ int wave_sums[16];  // 1024 / 64 = 16 waves

    const int t    = threadIdx.x;
    const int lane = t & 63;
    const int wave = t >> 6;
    const int base = t * SCAN_ITEMS;

    // init inv to "no column" (scatter below happens after two barriers)
    for (int r = t; r <= N; r += SCAN_THREADS) inv[r] = -1;

    float c_[SCAN_ITEMS], e_[SCAN_ITEMS];
    int   cnd[SCAN_ITEMS];

    int local = 0;
    #pragma unroll
    for (int i = 0; i < SCAN_ITEMS; i++) {
        float xv = x[base + i];
        float lo = fmaxf(EPS_F - xv, 0.0f) * 0.5f;
        float hi = fmaxf(xv - (1.0f - EPS_F), 0.0f) * 0.5f;
        c_[i] = xv + lo - hi;
        float ev = EPS_F - lo - hi;
        e_[i] = ev;
        cnd[i] = (ev >= 0.0f) ? 1 : 0;
        local += cnd[i];
    }

    #pragma unroll
    for (int i = 0; i < SCAN_ITEMS; i++) {
        center[base + i] = c_[i];
        err[base + i]    = e_[i];
    }

    // Wave-level inclusive scan of per-thread counts (width 64).
    int inc = local;
    #pragma unroll
    for (int off = 1; off < 64; off <<= 1) {
        int y = __shfl_up(inc, off, 64);
        if (lane >= off) inc += y;
    }
    if (lane == 63) wave_sums[wave] = inc;
    __syncthreads();

    if (t == 0) {
        int acc = 0;
        #pragma unroll
        for (int w = 0; w < 16; w++) {
            acc += wave_sums[w];
            wave_sums[w] = acc;  // inclusive
        }
    }
    __syncthreads();

    const int wave_off = (wave == 0) ? 0 : wave_sums[wave - 1];
    int run = wave_off + (inc - local);  // exclusive prefix for this thread

    #pragma unroll
    for (int i = 0; i < SCAN_ITEMS; i++) {
        run += cnd[i];
        if (cnd[i]) inv[run] = base + i;  // row `run` <- column base+i
    }
}

// -------------------------------------------------------------------------
// Kernel 2: one block per output row, linear write sweep (fill-like).
// Row 0 = center. Row r>=1 = zeros except column inv[r] = err[inv[r]].
// Consecutive blocks write consecutive 48 KB rows -> the global store
// pattern is a single linear sweep, same as the rocclr fill that measures
// 6.24 TB/s. 1024 threads x 3 float4 stores = one full row per block.
// -------------------------------------------------------------------------
__global__ __launch_bounds__(ROW_THREADS) void zono_write_row(
    float* __restrict__ out,
    const float* __restrict__ center,
    const float* __restrict__ err,
    const int*   __restrict__ inv,
    int N)
{
    const int row  = blockIdx.x;   // 0..N, one block per row
    const int nvec = N >> 2;       // float4s per row (3072)

    float4* __restrict__ dst =
        reinterpret_cast<float4*>(out + (size_t)row * (size_t)N);

    if (row == 0) {
        const float4* __restrict__ c4 =
            reinterpret_cast<const float4*>(center);
        for (int v = threadIdx.x; v < nvec; v += ROW_THREADS)
            dst[v] = c4[v];
    } else {
        const int colsel = inv[row];          // uniform per block; -1 = none
        const int v4sel  = (colsel >= 0) ? (colsel >> 2) : -1;
        const float ev   = (colsel >= 0) ? err[colsel] : 0.0f;
        for (int v = threadIdx.x; v < nvec; v += ROW_THREADS) {
            float4 z = make_float4(0.0f, 0.0f, 0.0f, 0.0f);
            if (v == v4sel) {
                const int c0 = v4sel << 2;
                z.x = (colsel == c0 + 0) ? ev : 0.0f;
                z.y = (colsel == c0 + 1) ? ev : 0.0f;
                z.z = (colsel == c0 + 2) ? ev : 0.0f;
                z.w = (colsel == c0 + 3) ? ev : 0.0f;
            }
            dst[v] = z;
        }
    }
}

// -------------------------------------------------------------------------
// Fallback path (round-1 passing version): memset + single-block finalize.
// Used only if the workspace is too small for center/err/inv.
// -------------------------------------------------------------------------
__global__ __launch_bounds__(SCAN_THREADS) void finalize_kernel(
    const float* __restrict__ x,
    float* __restrict__ out,
    int N)
{
    __shared__ int wave_sums[16];

    const int t    = threadIdx.x;
    const int lane = t & 63;
    const int wave = t >> 6;
    const int base = t * SCAN_ITEMS;

    float c_[SCAN_ITEMS], e_[SCAN_ITEMS];
    int   cnd[SCAN_ITEMS];

    int local = 0;
    #pragma unroll
    for (int i = 0; i < SCAN_ITEMS; i++) {
        float xv = x[base + i];
        float lo = fmaxf(EPS_F - xv, 0.0f) * 0.5f;
        float hi = fmaxf(xv - (1.0f - EPS_F), 0.0f) * 0.5f;
        c_[i] = xv + lo - hi;
        float ev = EPS_F - lo - hi;
        e_[i] = ev;
        cnd[i] = (ev >= 0.0f) ? 1 : 0;
        local += cnd[i];
    }

    int inc = local;
    #pragma unroll
    for (int off = 1; off < 64; off <<= 1) {
        int y = __shfl_up(inc, off, 64);
        if (lane >= off) inc += y;
    }
    if (lane == 63) wave_sums[wave] = inc;
    __syncthreads();

    if (t == 0) {
        int acc = 0;
        #pragma unroll
        for (int w = 0; w < 16; w++) {
            acc += wave_sums[w];
            wave_sums[w] = acc;
        }
    }
    __syncthreads();

    const int wave_off = (wave == 0) ? 0 : wave_sums[wave - 1];
    int run = wave_off + (inc - local);

    #pragma unroll
    for (int i = 0; i < SCAN_ITEMS; i++) {
        const int k = base + i;
        out[k] = c_[i];
        run += cnd[i];
        if (cnd[i]) {
            out[(size_t)run * (size_t)N + (size_t)k] = e_[i];
        }
    }
}

extern "C" void kernel_launch(void* const* d_in, const int* in_sizes, int n_in,
                              void* d_out, int out_size, void* d_ws, size_t ws_size,
                              hipStream_t stream)
{
    const float* x = (const float*)d_in[0];
    float* out = (float*)d_out;
    const int N = in_sizes[0];  // 12288

    // Workspace layout: center[N] f32 | err[N] f32 | inv[N+1] i32
    const size_t need_ws = (size_t)N * 4 + (size_t)N * 4 + (size_t)(N + 1) * 4;

    if (d_ws != nullptr && ws_size >= need_ws) {
        float* center = (float*)d_ws;
        float* err    = center + N;
        int*   inv    = (int*)(err + N);

        // 1) tiny single-block scan -> center/err/inv in workspace (~5 us)
        scan_kernel<<<1, SCAN_THREADS, 0, stream>>>(x, center, err, inv, N);

        // 2) one block per row, linear sweep: write all 604 MB exactly once.
        zono_write_row<<<N + 1, ROW_THREADS, 0, stream>>>(
            out, center, err, inv, N);
    } else {
        // Fallback: round-1 passing path (memset + single-block finalize).
        const size_t out_bytes = (size_t)(N + 1) * (size_t)N * sizeof(float);
        hipMemsetAsync(d_out, 0, out_bytes, stream);
        finalize_kernel<<<1, SCAN_THREADS, 0, stream>>>(x, out, N);
    }
}

// Round 4
// 579.074 us; speedup vs baseline: 1.0319x; 1.0319x over previous
//
#include <hip/hip_runtime.h>

#define EPS_F 0.1f
#define SCAN_THREADS 1024
#define SCAN_ITEMS 12   // N / SCAN_THREADS = 12288 / 1024

// -------------------------------------------------------------------------
// Kernel 1: single-block scan. Computes center/err per element, the
// inclusive cumsum of the selection mask (row assignment), and the INVERSE
// mapping inv[row] = column (or -1 if the row has no selected element).
// Outputs go to workspace: center[N] f32, err[N] f32, inv[N+1] i32.
// ~5 us (reads 48 KB, writes ~148 KB, all linear).
// -------------------------------------------------------------------------
__global__ __launch_bounds__(SCAN_THREADS) void scan_kernel(
    const float* __restrict__ x,
    float* __restrict__ center,
    float* __restrict__ err,
    int*   __restrict__ inv,
    int N)
{
    __shared__ int wave_sums[16];  // 1024 / 64 = 16 waves

    const int t    = threadIdx.x;
    const int lane = t & 63;
    const int wave = t >> 6;
    const int base = t * SCAN_ITEMS;

    // init inv to "no column" (scatter below happens after two barriers)
    for (int r = t; r <= N; r += SCAN_THREADS) inv[r] = -1;

    float c_[SCAN_ITEMS], e_[SCAN_ITEMS];
    int   cnd[SCAN_ITEMS];

    int local = 0;
    #pragma unroll
    for (int i = 0; i < SCAN_ITEMS; i++) {
        float xv = x[base + i];
        float lo = fmaxf(EPS_F - xv, 0.0f) * 0.5f;
        float hi = fmaxf(xv - (1.0f - EPS_F), 0.0f) * 0.5f;
        c_[i] = xv + lo - hi;
        float ev = EPS_F - lo - hi;
        e_[i] = ev;
        cnd[i] = (ev >= 0.0f) ? 1 : 0;
        local += cnd[i];
    }

    #pragma unroll
    for (int i = 0; i < SCAN_ITEMS; i++) {
        center[base + i] = c_[i];
        err[base + i]    = e_[i];
    }

    // Wave-level inclusive scan of per-thread counts (width 64).
    int inc = local;
    #pragma unroll
    for (int off = 1; off < 64; off <<= 1) {
        int y = __shfl_up(inc, off, 64);
        if (lane >= off) inc += y;
    }
    if (lane == 63) wave_sums[wave] = inc;
    __syncthreads();

    if (t == 0) {
        int acc = 0;
        #pragma unroll
        for (int w = 0; w < 16; w++) {
            acc += wave_sums[w];
            wave_sums[w] = acc;  // inclusive
        }
    }
    __syncthreads();

    const int wave_off = (wave == 0) ? 0 : wave_sums[wave - 1];
    int run = wave_off + (inc - local);  // exclusive prefix for this thread

    #pragma unroll
    for (int i = 0; i < SCAN_ITEMS; i++) {
        run += cnd[i];
        if (cnd[i]) inv[run] = base + i;  // row `run` <- column base+i
    }
}

// -------------------------------------------------------------------------
// Kernel 2: parallel finalize AFTER the memset. One thread per row-0
// float4 (3072 of them) and one thread per scattered element (12288).
// 48 blocks x 256 threads: the 12288 scattered partial-line stores spread
// across ~96 CUs instead of R1's single CU (which cost ~90 us).
// -------------------------------------------------------------------------
__global__ __launch_bounds__(256) void scatter_kernel(
    float* __restrict__ out,
    const float* __restrict__ center,
    const float* __restrict__ err,
    const int*   __restrict__ inv,
    int N)
{
    const int j    = blockIdx.x * 256 + threadIdx.x;
    const int nvec = N >> 2;  // 3072 float4s in row 0

    if (j < nvec) {
        reinterpret_cast<float4*>(out)[j] =
            reinterpret_cast<const float4*>(center)[j];
    }
    if (j < N) {
        const int r   = j + 1;       // rows 1..N
        const int col = inv[r];      // column holding this row's nonzero
        if (col >= 0)
            out[(size_t)r * (size_t)N + (size_t)col] = err[col];
    }
}

// -------------------------------------------------------------------------
// Fallback path (round-1 passing version): memset + single-block finalize.
// Used only if the workspace is too small for center/err/inv.
// -------------------------------------------------------------------------
__global__ __launch_bounds__(SCAN_THREADS) void finalize_kernel(
    const float* __restrict__ x,
    float* __restrict__ out,
    int N)
{
    __shared__ int wave_sums[16];

    const int t    = threadIdx.x;
    const int lane = t & 63;
    const int wave = t >> 6;
    const int base = t * SCAN_ITEMS;

    float c_[SCAN_ITEMS], e_[SCAN_ITEMS];
    int   cnd[SCAN_ITEMS];

    int local = 0;
    #pragma unroll
    for (int i = 0; i < SCAN_ITEMS; i++) {
        float xv = x[base + i];
        float lo = fmaxf(EPS_F - xv, 0.0f) * 0.5f;
        float hi = fmaxf(xv - (1.0f - EPS_F), 0.0f) * 0.5f;
        c_[i] = xv + lo - hi;
        float ev = EPS_F - lo - hi;
        e_[i] = ev;
        cnd[i] = (ev >= 0.0f) ? 1 : 0;
        local += cnd[i];
    }

    int inc = local;
    #pragma unroll
    for (int off = 1; off < 64; off <<= 1) {
        int y = __shfl_up(inc, off, 64);
        if (lane >= off) inc += y;
    }
    if (lane == 63) wave_sums[wave] = inc;
    __syncthreads();

    if (t == 0) {
        int acc = 0;
        #pragma unroll
        for (int w = 0; w < 16; w++) {
            acc += wave_sums[w];
            wave_sums[w] = acc;
        }
    }
    __syncthreads();

    const int wave_off = (wave == 0) ? 0 : wave_sums[wave - 1];
    int run = wave_off + (inc - local);

    #pragma unroll
    for (int i = 0; i < SCAN_ITEMS; i++) {
        const int k = base + i;
        out[k] = c_[i];
        run += cnd[i];
        if (cnd[i]) {
            out[(size_t)run * (size_t)N + (size_t)k] = e_[i];
        }
    }
}

extern "C" void kernel_launch(void* const* d_in, const int* in_sizes, int n_in,
                              void* d_out, int out_size, void* d_ws, size_t ws_size,
                              hipStream_t stream)
{
    const float* x = (const float*)d_in[0];
    float* out = (float*)d_out;
    const int N = in_sizes[0];  // 12288

    // Workspace layout: center[N] f32 | err[N] f32 | inv[N+1] i32
    const size_t need_ws = (size_t)N * 4 + (size_t)N * 4 + (size_t)(N + 1) * 4;
    const size_t out_bytes = (size_t)(N + 1) * (size_t)N * sizeof(float);

    if (d_ws != nullptr && ws_size >= need_ws) {
        float* center = (float*)d_ws;
        float* err    = center + N;
        int*   inv    = (int*)(err + N);

        // 1) proven 6.2 TB/s zero-fill of the 604 MB output (~97 us)
        hipMemsetAsync(d_out, 0, out_bytes, stream);

        // 2) tiny single-block scan -> center/err/inv in workspace (~5 us)
        scan_kernel<<<1, SCAN_THREADS, 0, stream>>>(x, center, err, inv, N);

        // 3) parallel finalize: row 0 + 12288 scattered stores (~15 us)
        const int blocks = (N + 255) / 256;  // 48
        scatter_kernel<<<blocks, 256, 0, stream>>>(out, center, err, inv, N);
    } else {
        // Fallback: round-1 passing path (memset + single-block finalize).
        hipMemsetAsync(d_out, 0, out_bytes, stream);
        finalize_kernel<<<1, SCAN_THREADS, 0, stream>>>(x, out, N);
    }
}